// Round 1
// baseline (183.383 us; speedup 1.0000x reference)
//
#include <hip/hip_runtime.h>
#include <math.h>

// Problem constants (reference: B=1024, C=10, H=30, W=30)
constexpr int BATCH = 1024;
constexpr int NC    = 10;     // n_colors / channels
constexpr int HW    = 900;    // 30*30 pixels per image
constexpr int GROUPS = HW / 4; // 225 float4 pixel-groups per image

// One block per batch image. Threads 0..224 each own 4 consecutive pixels
// (float4 loads, fully coalesced: channel stride 900 floats = 3600 B, all
// 16B-aligned). Block reduces all per-image quantities, then one set of
// atomics into the global accumulator:
//   acc[0] = sum of weighted CE over all pixels
//   acc[1] = count of exact-match images
//   acc[2] = count of (should_not_copy && did_copy) images
//   acc[3] = sum over images of ((changed - target_changed)/900)^2
//   acc[4] = total missing colors (tgt_present & !pred_present)
__global__ __launch_bounds__(256) void loss_main(
    const float* __restrict__ pred, const float* __restrict__ target,
    const float* __restrict__ inp, float* __restrict__ acc) {
  const int b = blockIdx.x;
  const int t = threadIdx.x;

  // Per-thread partials (identity values for idle threads t>=225)
  float ce_sum = 0.f;
  int all_pt = 1;   // AND over pixels: pred_idx == tgt_idx
  int any_ti = 0;   // OR  over pixels: tgt_idx != inp_idx
  int all_pi = 1;   // AND over pixels: pred_idx == inp_idx
  int changed = 0;  // count pred_idx != inp_idx
  int tchanged = 0; // count tgt_idx != inp_idx
  unsigned pmask = 0, tmask = 0; // color presence bitmasks

  if (t < GROUPS) {
    const size_t base = (size_t)b * NC * HW + (size_t)t * 4;
    float pv[NC][4];          // keep pred values for log-softmax 2nd pass
    float tmax[4]; int tidx[4];
    float gmax[4]; int gidx[4];
#pragma unroll
    for (int c = 0; c < NC; ++c) {
      const float4 p4 = *(const float4*)(pred + base + c * HW);
      const float4 t4 = *(const float4*)(target + base + c * HW);
      const float4 g4 = *(const float4*)(inp + base + c * HW);
      const float pc[4] = {p4.x, p4.y, p4.z, p4.w};
      const float tc[4] = {t4.x, t4.y, t4.z, t4.w};
      const float gc[4] = {g4.x, g4.y, g4.z, g4.w};
#pragma unroll
      for (int j = 0; j < 4; ++j) {
        pv[c][j] = pc[j];
        if (c == 0) {
          tmax[j] = tc[j]; tidx[j] = 0;
          gmax[j] = gc[j]; gidx[j] = 0;
        } else {
          if (tc[j] > tmax[j]) { tmax[j] = tc[j]; tidx[j] = c; } // strict > = first-index argmax
          if (gc[j] > gmax[j]) { gmax[j] = gc[j]; gidx[j] = c; }
        }
      }
    }
#pragma unroll
    for (int j = 0; j < 4; ++j) {
      // pred argmax + stable log-sum-exp
      float pmax = pv[0][j]; int pidx = 0;
#pragma unroll
      for (int c = 1; c < NC; ++c)
        if (pv[c][j] > pmax) { pmax = pv[c][j]; pidx = c; }
      float s = 0.f;
#pragma unroll
      for (int c = 0; c < NC; ++c) s += __expf(pv[c][j] - pmax);
      const float lse = pmax + __logf(s);
      // pred value at target index (cndmask chain; no dynamic reg indexing)
      float ptv = pv[0][j];
#pragma unroll
      for (int c = 1; c < NC; ++c)
        if (tidx[j] == c) ptv = pv[c][j];
      const float ce = lse - ptv;
      const int ti = tidx[j], gi = gidx[j];
      const float w = (pidx != ti) ? 5.0f : 1.0f; // 1 + 4*incorrect
      ce_sum += ce * w;
      all_pt &= (pidx == ti);
      any_ti |= (ti != gi);
      all_pi &= (pidx == gi);
      changed  += (pidx != gi);
      tchanged += (ti != gi);
      pmask |= 1u << pidx;
      tmask |= 1u << ti;
    }
  }

  // Wave(64)-level reduction
#pragma unroll
  for (int off = 32; off >= 1; off >>= 1) {
    ce_sum  += __shfl_down(ce_sum, off);
    all_pt  &= __shfl_down(all_pt, off);
    any_ti  |= __shfl_down(any_ti, off);
    all_pi  &= __shfl_down(all_pi, off);
    changed += __shfl_down(changed, off);
    tchanged+= __shfl_down(tchanged, off);
    pmask   |= __shfl_down(pmask, off);
    tmask   |= __shfl_down(tmask, off);
  }

  __shared__ float s_ce[4];
  __shared__ int s_apt[4], s_ati[4], s_api[4], s_ch[4], s_tch[4];
  __shared__ unsigned s_pm[4], s_tm[4];
  const int wave = t >> 6;
  if ((t & 63) == 0) {
    s_ce[wave] = ce_sum; s_apt[wave] = all_pt; s_ati[wave] = any_ti;
    s_api[wave] = all_pi; s_ch[wave] = changed; s_tch[wave] = tchanged;
    s_pm[wave] = pmask; s_tm[wave] = tmask;
  }
  __syncthreads();
  if (t == 0) {
    float ce = 0.f; int apt = 1, ati = 0, api = 1, ch = 0, tch = 0;
    unsigned pm = 0, tm = 0;
#pragma unroll
    for (int w = 0; w < 4; ++w) {
      ce += s_ce[w]; apt &= s_apt[w]; ati |= s_ati[w]; api &= s_api[w];
      ch += s_ch[w]; tch += s_tch[w]; pm |= s_pm[w]; tm |= s_tm[w];
    }
    atomicAdd(&acc[0], ce);
    atomicAdd(&acc[1], (float)apt);
    atomicAdd(&acc[2], (float)(ati & api));
    const float d = (float)(ch - tch) * (1.0f / (float)HW);
    atomicAdd(&acc[3], d * d);
    atomicAdd(&acc[4], (float)__popc(tm & ~pm));
  }
}

__global__ void loss_final(const float* __restrict__ acc, float* __restrict__ out) {
  const float ce_loss    = acc[0] * (1.0f / ((float)BATCH * (float)HW));
  const float exact_sum  = acc[1];
  const float exact_frac = exact_sum * (1.0f / (float)BATCH);
  const float copy_pen   = 5.0f * acc[2] * (1.0f / (float)BATCH);
  const float tdiff      = acc[3] * (1.0f / (float)BATCH);
  const float color_pen  = 0.1f * acc[4];
  float total = ce_loss - exact_frac + copy_pen + tdiff + color_pen;
  if (isnan(total)) total = 2.0f;
  else if (total > 100.0f) total = 10.0f;
  out[0] = total;
  out[1] = ce_loss;
  out[2] = copy_pen;
  out[3] = exact_frac;
  out[4] = exact_sum;
  out[5] = tdiff;
}

extern "C" void kernel_launch(void* const* d_in, const int* in_sizes, int n_in,
                              void* d_out, int out_size, void* d_ws, size_t ws_size,
                              hipStream_t stream) {
  const float* pred   = (const float*)d_in[0];
  const float* target = (const float*)d_in[1];
  const float* inp    = (const float*)d_in[2];
  float* acc = (float*)d_ws;
  // ws is re-poisoned to 0xAA before every launch — zero the accumulators.
  hipMemsetAsync(acc, 0, 5 * sizeof(float), stream);
  loss_main<<<dim3(BATCH), dim3(256), 0, stream>>>(pred, target, inp, acc);
  loss_final<<<dim3(1), dim3(1), 0, stream>>>(acc, (float*)d_out);
}